// Round 11
// baseline (303.139 us; speedup 1.0000x reference)
//
#include <hip/hip_runtime.h>
#include <math.h>

#define TOK    4096
#define DIM    1024
#define NHEAD  1002
#define NSHORT 1000
#define C0     9000
#define K0     256
#define C1     40257
#define K1     64

typedef __attribute__((ext_vector_type(8))) short short8;
typedef __attribute__((ext_vector_type(4))) float float4v;

__device__ __forceinline__ void gld_lds16(const void* g, void* l) {
    __builtin_amdgcn_global_load_lds(
        (const __attribute__((address_space(1))) unsigned int*)g,
        (__attribute__((address_space(3))) unsigned int*)l,
        16, 0, 0);
}

__device__ __forceinline__ unsigned short f2bf(float f) {
    unsigned int u = __float_as_uint(f);
    return (unsigned short)((u + 0x7FFFu + ((u >> 16) & 1u)) >> 16);
}

__device__ __forceinline__ float bf2f(unsigned short h) {
    return __uint_as_float(((unsigned int)h) << 16);
}

// -------- all fp32->bf16 casts (x + weights) in ONE launch + init ---------
#define S0E (TOK * DIM / 4)
#define S1E (S0E + NHEAD * DIM / 4)
#define S2E (S1E + K0 * DIM / 4)
#define S3E (S2E + C0 * K0 / 4)
#define S4E (S3E + K1 * DIM / 4)
#define S5E (S4E + C1 * K1 / 4)
__global__ __launch_bounds__(256) void megacast_kernel(
    const float* __restrict__ x, const float* __restrict__ W_head,
    const float* __restrict__ W0a, const float* __restrict__ W0b,
    const float* __restrict__ W1a, const float* __restrict__ W1b,
    unsigned short* __restrict__ xh, unsigned short* __restrict__ Wheadh,
    unsigned short* __restrict__ W0ah, unsigned short* __restrict__ W0bh,
    unsigned short* __restrict__ W1ah, unsigned short* __restrict__ W1bh,
    int* __restrict__ cnt, float* __restrict__ Shead,
    float* __restrict__ S0c, float* __restrict__ S1c, float* __restrict__ loss)
{
    int i = blockIdx.x * 256 + threadIdx.x;
    if (i == 0) { cnt[0] = 0; cnt[1] = 0; loss[0] = 0.f; }
    if (i < TOK / 4) {
        ((float4*)Shead)[i] = (float4){0.f, 0.f, 0.f, 0.f};
        ((float4*)S0c)[i]   = (float4){0.f, 0.f, 0.f, 0.f};
        ((float4*)S1c)[i]   = (float4){0.f, 0.f, 0.f, 0.f};
    }
    const float* src; unsigned short* dst; int off;
    if      (i < S0E) { src = x;      dst = xh;     off = i; }
    else if (i < S1E) { src = W_head; dst = Wheadh; off = i - S0E; }
    else if (i < S2E) { src = W0a;    dst = W0ah;   off = i - S1E; }
    else if (i < S3E) { src = W0b;    dst = W0bh;   off = i - S2E; }
    else if (i < S4E) { src = W1a;    dst = W1ah;   off = i - S3E; }
    else if (i < S5E) { src = W1b;    dst = W1bh;   off = i - S4E; }
    else return;
    float4 v = ((const float4*)src)[off];
    ushort4 o;
    o.x = f2bf(v.x); o.y = f2bf(v.y); o.z = f2bf(v.z); o.w = f2bf(v.w);
    ((ushort4*)dst)[off] = o;
}

// ---- 128x64x64 bf16 MFMA GEMM (async gld_lds staging), XCD-swizzled, ----
// ---- head-softmax-fused; blocks [672,688) do target classification. -----
__global__ __launch_bounds__(256, 3) void gemm_sw(
    const unsigned short* __restrict__ Ah,
    const unsigned short* __restrict__ Wheadh, const unsigned short* __restrict__ W0ah,
    const unsigned short* __restrict__ W1ah,
    const int* __restrict__ target,
    float* __restrict__ Shead, float* __restrict__ g0, float* __restrict__ g1,
    float* __restrict__ th,
    unsigned short* __restrict__ XA0h, unsigned short* __restrict__ XA1h,
    int* __restrict__ cnt, int* __restrict__ l0, int* __restrict__ l1)
{
    const int id = blockIdx.x;
    if (id >= 672) {
        int t = (id - 672) * 256 + threadIdx.x;
        if (t < TOK) {
            int tg = target[t];
            if (tg >= NSHORT && tg < NSHORT + C0) {
                int i = atomicAdd(&cnt[0], 1); l0[i] = t;
            } else if (tg >= NSHORT + C0) {
                int i = atomicAdd(&cnt[1], 1); l1[i] = t;
            }
        }
        return;
    }
    const int xcd = id & 7, j = id >> 3;
    const int bx = j % 21, by = xcd + 8 * (j / 21);

    const unsigned short* Bh; int nrows, bn, seg, ldY; unsigned short* Yh;
    if (bx < 16)      { seg = 0; Bh = Wheadh; nrows = NHEAD; bn = bx * 64;        Yh = nullptr; ldY = 0; }
    else if (bx < 20) { seg = 1; Bh = W0ah;   nrows = K0;    bn = (bx - 16) * 64; Yh = XA0h;    ldY = K0; }
    else              { seg = 2; Bh = W1ah;   nrows = K1;    bn = 0;              Yh = XA1h;    ldY = K1; }
    const int bm = by * 128;

    __shared__ short ldsA[2][8192];
    __shared__ short ldsB[2][4096];
    const int tid = threadIdx.x, wv = tid >> 6, lane = tid & 63;
    const int nn = lane & 15, q = lane >> 4;
    const int wr = wv >> 1, wc = wv & 1;

    float4v acc[4][2];
    #pragma unroll
    for (int i = 0; i < 4; ++i)
        #pragma unroll
        for (int jj = 0; jj < 2; ++jj) acc[i][jj] = (float4v){0.f, 0.f, 0.f, 0.f};

    auto stage = [&](int b, int kk) {
        #pragma unroll
        for (int i2 = 0; i2 < 6; ++i2) {
            int ch = wv * 6 + i2;
            if (ch < 16) {
                int rg = ch >> 1, kc = ch & 1;
                int row = bm + rg * 16 + nn;
                gld_lds16(Ah + (size_t)row * DIM + kk + kc * 32 + q * 8, &ldsA[b][ch * 512]);
            } else {
                int bc = ch - 16, rg = bc >> 1, kc = bc & 1;
                int row = bn + rg * 16 + nn;
                if (row > nrows - 1) row = nrows - 1;
                gld_lds16(Bh + (size_t)row * DIM + kk + kc * 32 + q * 8, &ldsB[b][bc * 512]);
            }
        }
    };

    int buf = 0;
    stage(0, 0);
    __syncthreads();
    for (int s = 0; s < DIM / 64; ++s) {
        if (s + 1 < DIM / 64) stage(buf ^ 1, (s + 1) * 64);
        short8 afr[4][2], bfr[2][2];
        #pragma unroll
        for (int i = 0; i < 4; ++i)
            #pragma unroll
            for (int kc = 0; kc < 2; ++kc)
                afr[i][kc] = *(const short8*)&ldsA[buf][((wr * 4 + i) * 2 + kc) * 512 + lane * 8];
        #pragma unroll
        for (int jj = 0; jj < 2; ++jj)
            #pragma unroll
            for (int kc = 0; kc < 2; ++kc)
                bfr[jj][kc] = *(const short8*)&ldsB[buf][((wc * 2 + jj) * 2 + kc) * 512 + lane * 8];
        #pragma unroll
        for (int kc = 0; kc < 2; ++kc)
            #pragma unroll
            for (int i = 0; i < 4; ++i)
                #pragma unroll
                for (int jj = 0; jj < 2; ++jj)
                    acc[i][jj] = __builtin_amdgcn_mfma_f32_16x16x32_bf16(afr[i][kc], bfr[jj][kc], acc[i][jj], 0, 0, 0);
        __syncthreads();
        buf ^= 1;
    }

    if (seg == 0) {
        #pragma unroll
        for (int i = 0; i < 4; ++i) {
            int rowr[4], tg[4];
            float s[4] = {0.f, 0.f, 0.f, 0.f};
            #pragma unroll
            for (int r = 0; r < 4; ++r) {
                rowr[r] = bm + wr * 64 + i * 16 + q * 4 + r;
                tg[r] = target[rowr[r]];
            }
            #pragma unroll
            for (int jj = 0; jj < 2; ++jj) {
                int col = bn + wc * 32 + jj * 16 + nn;
                bool cv = (col < NHEAD);
                #pragma unroll
                for (int r = 0; r < 4; ++r) {
                    float v = acc[i][jj][r];
                    if (cv) {
                        s[r] += __expf(v);
                        if (col == 1000) g0[rowr[r]] = v;
                        if (col == 1001) g1[rowr[r]] = v;
                        if (tg[r] < NSHORT && col == tg[r]) th[rowr[r]] = v;
                    }
                }
            }
            #pragma unroll
            for (int off = 1; off < 16; off <<= 1)
                #pragma unroll
                for (int r = 0; r < 4; ++r) s[r] += __shfl_xor(s[r], off, 64);
            if (nn == 0) {
                #pragma unroll
                for (int r = 0; r < 4; ++r) atomicAdd(&Shead[rowr[r]], s[r]);
            }
        }
    } else {
        #pragma unroll
        for (int i = 0; i < 4; ++i)
            #pragma unroll
            for (int jj = 0; jj < 2; ++jj) {
                int col = bn + wc * 32 + jj * 16 + nn;
                if (col < nrows) {
                    #pragma unroll
                    for (int r = 0; r < 4; ++r) {
                        int row = bm + wr * 64 + i * 16 + q * 4 + r;
                        Yh[(size_t)row * ldY + col] = f2bf(acc[i][jj][r]);
                    }
                }
            }
    }
}

// ------- cluster one-shot tile: 128 tokens x 64 classes per block ---------
// KT = K/64 k-rounds (dbuf iff KT>1). One (or KT) barrier(s) per block; exp
// partials atomicAdd'ed into per-token S. LDS/buf: A 16KB + B 8KB.
template<int K, int KT>
__global__ __launch_bounds__(256) void cluster_tile(
    const unsigned short* __restrict__ XAh, const unsigned short* __restrict__ Wbh,
    int C, const int* __restrict__ list, const int* __restrict__ cnt, int ci,
    float* __restrict__ S)
{
    constexpr int NB = (KT > 1) ? 2 : 1;
    const int n = cnt[ci];
    const int tb = blockIdx.x;
    if (tb * 128 >= n) return;
    const int ct = blockIdx.y;
    __shared__ short lds[NB * 12288];   // per buf: A 8192 + B 4096 shorts
    const int tid = threadIdx.x, wv = tid >> 6, lane = tid & 63;
    const int nn = lane & 15, q = lane >> 4;
    const int wr = wv >> 1, wc = wv & 1;

    auto stage = [&](int b, int kk) {
        #pragma unroll
        for (int i2 = 0; i2 < 6; ++i2) {
            int ch = wv * 6 + i2;
            if (ch < 16) {
                int rg = ch >> 1, kc = ch & 1;
                int iTok = tb * 128 + rg * 16 + nn;
                int tok = list[(iTok < n) ? iTok : (n - 1)];
                gld_lds16(XAh + (size_t)tok * K + kk + kc * 32 + q * 8,
                          &lds[b * 12288 + ch * 512]);
            } else {
                int bc = ch - 16, rg = bc >> 1, kc = bc & 1;
                int row = ct * 64 + rg * 16 + nn;
                if (row > C - 1) row = C - 1;
                gld_lds16(Wbh + (size_t)row * K + kk + kc * 32 + q * 8,
                          &lds[b * 12288 + 8192 + bc * 512]);
            }
        }
    };

    float4v acc[4][2];
    #pragma unroll
    for (int i = 0; i < 4; ++i)
        #pragma unroll
        for (int jj = 0; jj < 2; ++jj) acc[i][jj] = (float4v){0.f, 0.f, 0.f, 0.f};

    stage(0, 0);
    __syncthreads();
    for (int s = 0; s < KT; ++s) {
        if (s + 1 < KT) stage((s + 1) & 1, (s + 1) * 64);
        const int buf = (s & 1) * 12288;
        short8 afr[4][2], bfr[2][2];
        #pragma unroll
        for (int i = 0; i < 4; ++i)
            #pragma unroll
            for (int kc = 0; kc < 2; ++kc)
                afr[i][kc] = *(const short8*)&lds[buf + ((wr * 4 + i) * 2 + kc) * 512 + lane * 8];
        #pragma unroll
        for (int jj = 0; jj < 2; ++jj)
            #pragma unroll
            for (int kc = 0; kc < 2; ++kc)
                bfr[jj][kc] = *(const short8*)&lds[buf + 8192 + ((wc * 2 + jj) * 2 + kc) * 512 + lane * 8];
        #pragma unroll
        for (int kc = 0; kc < 2; ++kc)
            #pragma unroll
            for (int i = 0; i < 4; ++i)
                #pragma unroll
                for (int jj = 0; jj < 2; ++jj)
                    acc[i][jj] = __builtin_amdgcn_mfma_f32_16x16x32_bf16(afr[i][kc], bfr[jj][kc], acc[i][jj], 0, 0, 0);
        __syncthreads();
    }

    // exp + mask + merge column halves (jj), reduce across 16 class lanes
    float* red = (float*)lds;           // 256 floats, lds reusable post-barrier
    #pragma unroll
    for (int i = 0; i < 4; ++i) {
        float s[4];
        #pragma unroll
        for (int r = 0; r < 4; ++r) {
            float v = 0.f;
            #pragma unroll
            for (int jj = 0; jj < 2; ++jj) {
                int j = ct * 64 + wc * 32 + jj * 16 + nn;
                if (j < C) v += __expf(acc[i][jj][r]);
            }
            s[r] = v;
        }
        #pragma unroll
        for (int off = 1; off < 16; off <<= 1)
            #pragma unroll
            for (int r = 0; r < 4; ++r) s[r] += __shfl_xor(s[r], off, 64);
        if (nn == 0) {
            #pragma unroll
            for (int r = 0; r < 4; ++r)
                red[(wr * 2 + wc) * 64 + i * 16 + q * 4 + r] = s[r];
        }
    }
    __syncthreads();
    if (tid < 128) {
        int iTok = tb * 128 + tid;
        if (iTok < n) {
            float v = red[(tid >> 6) * 128 + (tid & 63)]
                    + red[(tid >> 6) * 128 + 64 + (tid & 63)];
            atomicAdd(&S[list[iTok]], v);
        }
    }
}

// ------- finish: shortlist out + cluster target dot/S/gate + loss ---------
__global__ __launch_bounds__(256) void finish_kernel(
    const unsigned short* __restrict__ XA0h, const unsigned short* __restrict__ W0bh,
    const unsigned short* __restrict__ XA1h, const unsigned short* __restrict__ W1bh,
    const int* __restrict__ l0, const int* __restrict__ l1,
    const int* __restrict__ cnt, const int* __restrict__ target,
    const float* __restrict__ S0c, const float* __restrict__ S1c,
    const float* __restrict__ Shead, const float* __restrict__ g0,
    const float* __restrict__ g1, const float* __restrict__ th,
    float* __restrict__ out, float* __restrict__ loss)
{
    const int y = blockIdx.y;
    const int tid = threadIdx.x, wv = tid >> 6, lane = tid & 63;
    float contrib = 0.f;
    if (y == 2) {
        int t = blockIdx.x * 256 + tid;
        if (t < TOK) {
            int tg = target[t];
            if (tg < NSHORT) {
                float v = th[t] - logf(Shead[t]);
                out[t] = v;
                contrib = v;
            }
        }
    } else {
        const int ci = y;
        const int n = cnt[ci];
        int i = blockIdx.x * 4 + wv;
        if (i < n) {
            const int* list = ci ? l1 : l0;
            int tok = list[i];
            float dot = 0.f;
            if (ci == 0) {
                int tg = target[tok] - NSHORT;
                const unsigned short* xp = XA0h + (size_t)tok * K0;
                const unsigned short* wp = W0bh + (size_t)tg * K0;
                #pragma unroll
                for (int k = 0; k < K0 / 64; ++k)
                    dot += bf2f(xp[lane + k * 64]) * bf2f(wp[lane + k * 64]);
            } else {
                int tg = target[tok] - (NSHORT + C0);
                dot = bf2f(XA1h[(size_t)tok * K1 + lane]) * bf2f(W1bh[(size_t)tg * K1 + lane]);
            }
            #pragma unroll
            for (int off = 32; off; off >>= 1) dot += __shfl_xor(dot, off, 64);
            if (lane == 0) {
                float S = ci ? S1c[tok] : S0c[tok];
                float gate = (ci ? g1[tok] : g0[tok]) - logf(Shead[tok]);
                float v = dot - logf(S) + gate;
                out[tok] = v;
                contrib = v;
            }
        }
    }
    __shared__ float red[4];
    #pragma unroll
    for (int off = 32; off; off >>= 1) contrib += __shfl_xor(contrib, off, 64);
    if (lane == 0) red[wv] = contrib;
    __syncthreads();
    if (tid == 0) {
        float t = red[0] + red[1] + red[2] + red[3];
        if (t != 0.f) atomicAdd(loss, -t / (float)TOK);
    }
}

extern "C" void kernel_launch(void* const* d_in, const int* in_sizes, int n_in,
                              void* d_out, int out_size, void* d_ws, size_t ws_size,
                              hipStream_t stream) {
    const float* x      = (const float*)d_in[0];
    const int*   target = (const int*)  d_in[1];
    const float* W_head = (const float*)d_in[2];
    const float* W0a    = (const float*)d_in[3];
    const float* W0b    = (const float*)d_in[4];
    const float* W1a    = (const float*)d_in[5];
    const float* W1b    = (const float*)d_in[6];
    float* out  = (float*)d_out;
    float* loss = out + TOK;

    float* ws     = (float*)d_ws;
    float* Shead  = ws;                               // 4096
    float* g0     = Shead + TOK;                      // 4096
    float* g1     = g0 + TOK;                         // 4096
    float* th     = g1 + TOK;                         // 4096
    float* S0c    = th + TOK;                         // 4096
    float* S1c    = S0c + TOK;                        // 4096
    unsigned short* xh     = (unsigned short*)(S1c + TOK);
    unsigned short* Wheadh = xh + (size_t)TOK * DIM;
    unsigned short* W0ah   = Wheadh + (size_t)NHEAD * DIM;
    unsigned short* W0bh   = W0ah + (size_t)K0 * DIM;
    unsigned short* W1ah   = W0bh + (size_t)C0 * K0;
    unsigned short* W1bh   = W1ah + (size_t)K1 * DIM;
    unsigned short* XA0h   = W1bh + (size_t)C1 * K1;
    unsigned short* XA1h   = XA0h + (size_t)TOK * K0;
    int* cnt = (int*)(XA1h + (size_t)TOK * K1);
    int* l0  = cnt + 8;
    int* l1  = l0 + TOK;

    megacast_kernel<<<(S5E + 255) / 256, 256, 0, stream>>>(
        x, W_head, W0a, W0b, W1a, W1b, xh, Wheadh, W0ah, W0bh, W1ah, W1bh,
        cnt, Shead, S0c, S1c, loss);

    gemm_sw<<<688, 256, 0, stream>>>(
        xh, Wheadh, W0ah, W1ah, target, Shead, g0, g1, th, XA0h, XA1h,
        cnt, l0, l1);

    // cluster1: K=64 one-shot tiles, grid 32 token-tiles x 630 class-tiles
    cluster_tile<K1, 1><<<dim3(TOK / 128, (C1 + 63) / 64), 256, 0, stream>>>(
        XA1h, W1bh, C1, l1, cnt, 1, S1c);
    // cluster0: K=256, 4 dbuf k-rounds, grid 32 x 141
    cluster_tile<K0, 4><<<dim3(TOK / 128, (C0 + 63) / 64), 256, 0, stream>>>(
        XA0h, W0bh, C0, l0, cnt, 0, S0c);

    finish_kernel<<<dim3(1024, 3), 256, 0, stream>>>(
        XA0h, W0bh, XA1h, W1bh, l0, l1, cnt, target, S0c, S1c,
        Shead, g0, g1, th, out, loss);
}

// Round 12
// 223.619 us; speedup vs baseline: 1.3556x; 1.3556x over previous
//
#include <hip/hip_runtime.h>
#include <math.h>

#define TOK    4096
#define DIM    1024
#define NHEAD  1002
#define NSHORT 1000
#define C0     9000
#define K0     256
#define C1     40257
#define K1     64
#define SP0    64
#define SP1    64
#define PS     64

typedef __attribute__((ext_vector_type(8))) short short8;
typedef __attribute__((ext_vector_type(4))) float float4v;

__device__ __forceinline__ void gld_lds16(const void* g, void* l) {
    __builtin_amdgcn_global_load_lds(
        (const __attribute__((address_space(1))) unsigned int*)g,
        (__attribute__((address_space(3))) unsigned int*)l,
        16, 0, 0);
}

__device__ __forceinline__ unsigned short f2bf(float f) {
    unsigned int u = __float_as_uint(f);
    return (unsigned short)((u + 0x7FFFu + ((u >> 16) & 1u)) >> 16);
}

__device__ __forceinline__ float bf2f(unsigned short h) {
    return __uint_as_float(((unsigned int)h) << 16);
}

// -------- all fp32->bf16 casts (x + weights) in ONE launch + init ---------
#define S0E (TOK * DIM / 4)
#define S1E (S0E + NHEAD * DIM / 4)
#define S2E (S1E + K0 * DIM / 4)
#define S3E (S2E + C0 * K0 / 4)
#define S4E (S3E + K1 * DIM / 4)
#define S5E (S4E + C1 * K1 / 4)
__global__ __launch_bounds__(256) void megacast_kernel(
    const float* __restrict__ x, const float* __restrict__ W_head,
    const float* __restrict__ W0a, const float* __restrict__ W0b,
    const float* __restrict__ W1a, const float* __restrict__ W1b,
    unsigned short* __restrict__ xh, unsigned short* __restrict__ Wheadh,
    unsigned short* __restrict__ W0ah, unsigned short* __restrict__ W0bh,
    unsigned short* __restrict__ W1ah, unsigned short* __restrict__ W1bh,
    int* __restrict__ cnt, float* __restrict__ Shead, float* __restrict__ loss)
{
    int i = blockIdx.x * 256 + threadIdx.x;
    if (i == 0) { cnt[0] = 0; cnt[1] = 0; loss[0] = 0.f; }
    if (i < TOK / 4) ((float4*)Shead)[i] = (float4){0.f, 0.f, 0.f, 0.f};
    const float* src; unsigned short* dst; int off;
    if      (i < S0E) { src = x;      dst = xh;     off = i; }
    else if (i < S1E) { src = W_head; dst = Wheadh; off = i - S0E; }
    else if (i < S2E) { src = W0a;    dst = W0ah;   off = i - S1E; }
    else if (i < S3E) { src = W0b;    dst = W0bh;   off = i - S2E; }
    else if (i < S4E) { src = W1a;    dst = W1ah;   off = i - S3E; }
    else if (i < S5E) { src = W1b;    dst = W1bh;   off = i - S4E; }
    else return;
    float4 v = ((const float4*)src)[off];
    ushort4 o;
    o.x = f2bf(v.x); o.y = f2bf(v.y); o.z = f2bf(v.z); o.w = f2bf(v.w);
    ((ushort4*)dst)[off] = o;
}

// ---- 128x64x64 bf16 MFMA GEMM (async gld_lds staging), XCD-swizzled, ----
// ---- head-softmax-fused; blocks [672,688) do target classification. -----
__global__ __launch_bounds__(256, 3) void gemm_sw(
    const unsigned short* __restrict__ Ah,
    const unsigned short* __restrict__ Wheadh, const unsigned short* __restrict__ W0ah,
    const unsigned short* __restrict__ W1ah,
    const int* __restrict__ target,
    float* __restrict__ Shead, float* __restrict__ g0, float* __restrict__ g1,
    float* __restrict__ th,
    unsigned short* __restrict__ XA0h, unsigned short* __restrict__ XA1h,
    int* __restrict__ cnt, int* __restrict__ l0, int* __restrict__ l1)
{
    const int id = blockIdx.x;
    if (id >= 672) {
        int t = (id - 672) * 256 + threadIdx.x;
        if (t < TOK) {
            int tg = target[t];
            if (tg >= NSHORT && tg < NSHORT + C0) {
                int i = atomicAdd(&cnt[0], 1); l0[i] = t;
            } else if (tg >= NSHORT + C0) {
                int i = atomicAdd(&cnt[1], 1); l1[i] = t;
            }
        }
        return;
    }
    const int xcd = id & 7, j = id >> 3;
    const int bx = j % 21, by = xcd + 8 * (j / 21);

    const unsigned short* Bh; int nrows, bn, seg, ldY; unsigned short* Yh;
    if (bx < 16)      { seg = 0; Bh = Wheadh; nrows = NHEAD; bn = bx * 64;        Yh = nullptr; ldY = 0; }
    else if (bx < 20) { seg = 1; Bh = W0ah;   nrows = K0;    bn = (bx - 16) * 64; Yh = XA0h;    ldY = K0; }
    else              { seg = 2; Bh = W1ah;   nrows = K1;    bn = 0;              Yh = XA1h;    ldY = K1; }
    const int bm = by * 128;

    __shared__ short ldsA[2][8192];
    __shared__ short ldsB[2][4096];
    const int tid = threadIdx.x, wv = tid >> 6, lane = tid & 63;
    const int nn = lane & 15, q = lane >> 4;
    const int wr = wv >> 1, wc = wv & 1;

    float4v acc[4][2];
    #pragma unroll
    for (int i = 0; i < 4; ++i)
        #pragma unroll
        for (int jj = 0; jj < 2; ++jj) acc[i][jj] = (float4v){0.f, 0.f, 0.f, 0.f};

    auto stage = [&](int b, int kk) {
        #pragma unroll
        for (int i2 = 0; i2 < 6; ++i2) {
            int ch = wv * 6 + i2;
            if (ch < 16) {
                int rg = ch >> 1, kc = ch & 1;
                int row = bm + rg * 16 + nn;
                gld_lds16(Ah + (size_t)row * DIM + kk + kc * 32 + q * 8, &ldsA[b][ch * 512]);
            } else {
                int bc = ch - 16, rg = bc >> 1, kc = bc & 1;
                int row = bn + rg * 16 + nn;
                if (row > nrows - 1) row = nrows - 1;
                gld_lds16(Bh + (size_t)row * DIM + kk + kc * 32 + q * 8, &ldsB[b][bc * 512]);
            }
        }
    };

    int buf = 0;
    stage(0, 0);
    __syncthreads();
    for (int s = 0; s < DIM / 64; ++s) {
        if (s + 1 < DIM / 64) stage(buf ^ 1, (s + 1) * 64);
        short8 afr[4][2], bfr[2][2];
        #pragma unroll
        for (int i = 0; i < 4; ++i)
            #pragma unroll
            for (int kc = 0; kc < 2; ++kc)
                afr[i][kc] = *(const short8*)&ldsA[buf][((wr * 4 + i) * 2 + kc) * 512 + lane * 8];
        #pragma unroll
        for (int jj = 0; jj < 2; ++jj)
            #pragma unroll
            for (int kc = 0; kc < 2; ++kc)
                bfr[jj][kc] = *(const short8*)&ldsB[buf][((wc * 2 + jj) * 2 + kc) * 512 + lane * 8];
        #pragma unroll
        for (int kc = 0; kc < 2; ++kc)
            #pragma unroll
            for (int i = 0; i < 4; ++i)
                #pragma unroll
                for (int jj = 0; jj < 2; ++jj)
                    acc[i][jj] = __builtin_amdgcn_mfma_f32_16x16x32_bf16(afr[i][kc], bfr[jj][kc], acc[i][jj], 0, 0, 0);
        __syncthreads();
        buf ^= 1;
    }

    if (seg == 0) {
        #pragma unroll
        for (int i = 0; i < 4; ++i) {
            int rowr[4], tg[4];
            float s[4] = {0.f, 0.f, 0.f, 0.f};
            #pragma unroll
            for (int r = 0; r < 4; ++r) {
                rowr[r] = bm + wr * 64 + i * 16 + q * 4 + r;
                tg[r] = target[rowr[r]];
            }
            #pragma unroll
            for (int jj = 0; jj < 2; ++jj) {
                int col = bn + wc * 32 + jj * 16 + nn;
                bool cv = (col < NHEAD);
                #pragma unroll
                for (int r = 0; r < 4; ++r) {
                    float v = acc[i][jj][r];
                    if (cv) {
                        s[r] += __expf(v);
                        if (col == 1000) g0[rowr[r]] = v;
                        if (col == 1001) g1[rowr[r]] = v;
                        if (tg[r] < NSHORT && col == tg[r]) th[rowr[r]] = v;
                    }
                }
            }
            #pragma unroll
            for (int off = 1; off < 16; off <<= 1)
                #pragma unroll
                for (int r = 0; r < 4; ++r) s[r] += __shfl_xor(s[r], off, 64);
            if (nn == 0) {
                #pragma unroll
                for (int r = 0; r < 4; ++r) atomicAdd(&Shead[rowr[r]], s[r]);
            }
        }
    } else {
        #pragma unroll
        for (int i = 0; i < 4; ++i)
            #pragma unroll
            for (int jj = 0; jj < 2; ++jj) {
                int col = bn + wc * 32 + jj * 16 + nn;
                if (col < nrows) {
                    #pragma unroll
                    for (int r = 0; r < 4; ++r) {
                        int row = bm + wr * 64 + i * 16 + q * 4 + r;
                        Yh[(size_t)row * ldY + col] = f2bf(acc[i][jj][r]);
                    }
                }
            }
    }
}

// ------- cluster exp-sum: persistent LDS-staged MFMA + exp ----------------
// Block covers MT*64 tokens (4 waves, each MT tiles of 16; A in registers,
// amortized over the class stripe). B staged via gld_lds dbuf, G ctiles/buf.
// cluster0: MT=2, G=2 -> 32 KB. cluster1: MT=4, G=4 -> 16 KB (8 blk/CU).
template<int K, int G, int MT>
__global__ __launch_bounds__(256) void cluster_lse(
    const unsigned short* __restrict__ XAh, const unsigned short* __restrict__ Wbh,
    int C, const int* __restrict__ list, const int* __restrict__ cnt, int ci,
    int tps, float* __restrict__ psum)
{
    constexpr int NCH = K / 32;
    constexpr int CPB = G * NCH;
    constexpr int TT = MT * 64;
    const int n = cnt[ci];
    if ((int)blockIdx.x * TT >= n) return;
    __shared__ short lds[2][CPB * 512];
    const int tid = threadIdx.x, wv = tid >> 6, lane = tid & 63;
    const int m = lane & 15, q = lane >> 4;
    const int nT = (C + 15) / 16;
    const int sp = blockIdx.y;
    const int T0 = sp * tps;
    const int T1 = min(T0 + tps, nT);
    if (T0 >= nT) return;

    short8 a[MT][NCH];
    #pragma unroll
    for (int t = 0; t < MT; ++t) {
        int iTok = blockIdx.x * TT + t * 64 + wv * 16 + m;
        int tok = list[(iTok < n) ? iTok : (n - 1)];
        const unsigned short* ap = XAh + (size_t)tok * K + q * 8;
        #pragma unroll
        for (int kc = 0; kc < NCH; ++kc) a[t][kc] = *(const short8*)(ap + kc * 32);
    }

    float s[MT][4] = {};

    auto stage = [&](int b, int Tb) {
        #pragma unroll
        for (int i = 0; i < CPB / 4; ++i) {
            int ch = wv * (CPB / 4) + i;
            int g = ch / NCH, kc = ch % NCH;
            int row = (Tb + g) * 16 + m;
            if (row > C - 1) row = C - 1;
            gld_lds16(Wbh + (size_t)row * K + kc * 32 + q * 8, &lds[b][ch * 512]);
        }
    };

    int buf = 0;
    stage(0, T0);
    __syncthreads();
    for (int Tb = T0; Tb < T1; Tb += G) {
        if (Tb + G < T1) stage(buf ^ 1, Tb + G);
        #pragma unroll
        for (int g = 0; g < G; ++g) {
            if (Tb + g < T1) {
                float4v av[MT];
                #pragma unroll
                for (int t = 0; t < MT; ++t) av[t] = (float4v){0.f, 0.f, 0.f, 0.f};
                #pragma unroll
                for (int kc = 0; kc < NCH; ++kc) {
                    short8 bfr = *(const short8*)&lds[buf][(g * NCH + kc) * 512 + lane * 8];
                    #pragma unroll
                    for (int t = 0; t < MT; ++t)
                        av[t] = __builtin_amdgcn_mfma_f32_16x16x32_bf16(a[t][kc], bfr, av[t], 0, 0, 0);
                }
                int jcl = (Tb + g) * 16 + m;
                if (jcl < C) {
                    #pragma unroll
                    for (int t = 0; t < MT; ++t)
                        #pragma unroll
                        for (int r = 0; r < 4; ++r) s[t][r] += __expf(av[t][r]);
                }
            }
        }
        __syncthreads();
        buf ^= 1;
    }
    #pragma unroll
    for (int off = 1; off < 16; off <<= 1)
        #pragma unroll
        for (int t = 0; t < MT; ++t)
            #pragma unroll
            for (int r = 0; r < 4; ++r)
                s[t][r] += __shfl_xor(s[t][r], off, 64);
    if (m == 0) {
        #pragma unroll
        for (int t = 0; t < MT; ++t)
            #pragma unroll
            for (int r = 0; r < 4; ++r) {
                int r0 = blockIdx.x * TT + t * 64 + wv * 16 + q * 4 + r;
                if (r0 < n) psum[(size_t)r0 * PS + sp] = s[t][r];
            }
    }
}

// ------- finish: shortlist out + cluster target dot/psum/gate + loss ------
__global__ __launch_bounds__(256) void finish_kernel(
    const unsigned short* __restrict__ XA0h, const unsigned short* __restrict__ W0bh,
    const unsigned short* __restrict__ XA1h, const unsigned short* __restrict__ W1bh,
    const int* __restrict__ l0, const int* __restrict__ l1,
    const int* __restrict__ cnt, const int* __restrict__ target,
    const float* __restrict__ psum0, const float* __restrict__ psum1,
    const float* __restrict__ Shead, const float* __restrict__ g0,
    const float* __restrict__ g1, const float* __restrict__ th,
    int tps0, int tps1, float* __restrict__ out, float* __restrict__ loss)
{
    const int y = blockIdx.y;
    const int tid = threadIdx.x, wv = tid >> 6, lane = tid & 63;
    float contrib = 0.f;
    if (y == 2) {
        int t = blockIdx.x * 256 + tid;
        if (t < TOK) {
            int tg = target[t];
            if (tg < NSHORT) {
                float v = th[t] - logf(Shead[t]);
                out[t] = v;
                contrib = v;
            }
        }
    } else {
        const int ci = y;
        const int n = cnt[ci];
        int i = blockIdx.x * 4 + wv;
        if (i < n) {
            const int* list = ci ? l1 : l0;
            int tok = list[i];
            float dot = 0.f, S = 0.f;
            if (ci == 0) {
                int tg = target[tok] - NSHORT;
                const unsigned short* xp = XA0h + (size_t)tok * K0;
                const unsigned short* wp = W0bh + (size_t)tg * K0;
                #pragma unroll
                for (int k = 0; k < K0 / 64; ++k)
                    dot += bf2f(xp[lane + k * 64]) * bf2f(wp[lane + k * 64]);
                int nT = (C0 + 15) / 16;
                if (lane * tps0 < nT) S = psum0[(size_t)i * PS + lane];
            } else {
                int tg = target[tok] - (NSHORT + C0);
                dot = bf2f(XA1h[(size_t)tok * K1 + lane]) * bf2f(W1bh[(size_t)tg * K1 + lane]);
                int nT = (C1 + 15) / 16;
                if (lane * tps1 < nT) S = psum1[(size_t)i * PS + lane];
            }
            #pragma unroll
            for (int off = 32; off; off >>= 1) {
                dot += __shfl_xor(dot, off, 64);
                S   += __shfl_xor(S, off, 64);
            }
            if (lane == 0) {
                float gate = (ci ? g1[tok] : g0[tok]) - logf(Shead[tok]);
                float v = dot - logf(S) + gate;
                out[tok] = v;
                contrib = v;
            }
        }
    }
    __shared__ float red[4];
    #pragma unroll
    for (int off = 32; off; off >>= 1) contrib += __shfl_xor(contrib, off, 64);
    if (lane == 0) red[wv] = contrib;
    __syncthreads();
    if (tid == 0) {
        float t = red[0] + red[1] + red[2] + red[3];
        if (t != 0.f) atomicAdd(loss, -t / (float)TOK);
    }
}

extern "C" void kernel_launch(void* const* d_in, const int* in_sizes, int n_in,
                              void* d_out, int out_size, void* d_ws, size_t ws_size,
                              hipStream_t stream) {
    const float* x      = (const float*)d_in[0];
    const int*   target = (const int*)  d_in[1];
    const float* W_head = (const float*)d_in[2];
    const float* W0a    = (const float*)d_in[3];
    const float* W0b    = (const float*)d_in[4];
    const float* W1a    = (const float*)d_in[5];
    const float* W1b    = (const float*)d_in[6];
    float* out  = (float*)d_out;
    float* loss = out + TOK;

    float* ws     = (float*)d_ws;
    float* Shead  = ws;                               // 4096
    float* g0     = Shead + TOK;                      // 4096
    float* g1     = g0 + TOK;                         // 4096
    float* th     = g1 + TOK;                         // 4096
    float* psum0  = th + TOK;                         // 4096*64
    float* psum1  = psum0 + (size_t)TOK * PS;         // 4096*64
    unsigned short* xh     = (unsigned short*)(psum1 + (size_t)TOK * PS);
    unsigned short* Wheadh = xh + (size_t)TOK * DIM;
    unsigned short* W0ah   = Wheadh + (size_t)NHEAD * DIM;
    unsigned short* W0bh   = W0ah + (size_t)K0 * DIM;
    unsigned short* W1ah   = W0bh + (size_t)C0 * K0;
    unsigned short* W1bh   = W1ah + (size_t)K1 * DIM;
    unsigned short* XA0h   = W1bh + (size_t)C1 * K1;
    unsigned short* XA1h   = XA0h + (size_t)TOK * K0;
    int* cnt = (int*)(XA1h + (size_t)TOK * K1);
    int* l0  = cnt + 8;
    int* l1  = l0 + TOK;

    int tps0 = ((C0 + 15) / 16 + SP0 - 1) / SP0;   // 9
    int tps1 = ((C1 + 15) / 16 + SP1 - 1) / SP1;   // 40

    megacast_kernel<<<(S5E + 255) / 256, 256, 0, stream>>>(
        x, W_head, W0a, W0b, W1a, W1b, xh, Wheadh, W0ah, W0bh, W1ah, W1bh,
        cnt, Shead, loss);

    gemm_sw<<<688, 256, 0, stream>>>(
        xh, Wheadh, W0ah, W1ah, target, Shead, g0, g1, th, XA0h, XA1h,
        cnt, l0, l1);

    // cluster0: K=256, MT=2 (128 tok/block), G=2 (32 KB)  -> grid (32, 64)
    cluster_lse<K0, 2, 2><<<dim3(TOK / 128, SP0), 256, 0, stream>>>(
        XA0h, W0bh, C0, l0, cnt, 0, tps0, psum0);
    // cluster1: K=64, MT=4 (256 tok/block), G=4 (16 KB)   -> grid (16, 64)
    cluster_lse<K1, 4, 4><<<dim3(TOK / 256, SP1), 256, 0, stream>>>(
        XA1h, W1bh, C1, l1, cnt, 1, tps1, psum1);

    finish_kernel<<<dim3(1024, 3), 256, 0, stream>>>(
        XA0h, W0bh, XA1h, W1bh, l0, l1, cnt, target, psum0, psum1,
        Shead, g0, g1, th, tps0, tps1, out, loss);
}

// Round 13
// 186.747 us; speedup vs baseline: 1.6233x; 1.1974x over previous
//
#include <hip/hip_runtime.h>
#include <math.h>

#define TOK    4096
#define DIM    1024
#define NHEAD  1002
#define NSHORT 1000
#define C0     9000
#define K0     256
#define C1     40257
#define K1     64
#define SP0    64
#define SP1    64
#define PS     64

typedef __attribute__((ext_vector_type(8))) short short8;
typedef __attribute__((ext_vector_type(4))) float float4v;

__device__ __forceinline__ void gld_lds16(const void* g, void* l) {
    __builtin_amdgcn_global_load_lds(
        (const __attribute__((address_space(1))) unsigned int*)g,
        (__attribute__((address_space(3))) unsigned int*)l,
        16, 0, 0);
}

__device__ __forceinline__ unsigned short f2bf(float f) {
    unsigned int u = __float_as_uint(f);
    return (unsigned short)((u + 0x7FFFu + ((u >> 16) & 1u)) >> 16);
}

__device__ __forceinline__ float bf2f(unsigned short h) {
    return __uint_as_float(((unsigned int)h) << 16);
}

// -------- all fp32->bf16 casts (x + weights) in ONE launch + init ---------
#define S0E (TOK * DIM / 4)
#define S1E (S0E + NHEAD * DIM / 4)
#define S2E (S1E + K0 * DIM / 4)
#define S3E (S2E + C0 * K0 / 4)
#define S4E (S3E + K1 * DIM / 4)
#define S5E (S4E + C1 * K1 / 4)
__global__ __launch_bounds__(256) void megacast_kernel(
    const float* __restrict__ x, const float* __restrict__ W_head,
    const float* __restrict__ W0a, const float* __restrict__ W0b,
    const float* __restrict__ W1a, const float* __restrict__ W1b,
    unsigned short* __restrict__ xh, unsigned short* __restrict__ Wheadh,
    unsigned short* __restrict__ W0ah, unsigned short* __restrict__ W0bh,
    unsigned short* __restrict__ W1ah, unsigned short* __restrict__ W1bh,
    int* __restrict__ cnt, float* __restrict__ Shead, float* __restrict__ loss)
{
    int i = blockIdx.x * 256 + threadIdx.x;
    if (i == 0) { cnt[0] = 0; cnt[1] = 0; loss[0] = 0.f; }
    if (i < TOK / 4) ((float4*)Shead)[i] = (float4){0.f, 0.f, 0.f, 0.f};
    const float* src; unsigned short* dst; int off;
    if      (i < S0E) { src = x;      dst = xh;     off = i; }
    else if (i < S1E) { src = W_head; dst = Wheadh; off = i - S0E; }
    else if (i < S2E) { src = W0a;    dst = W0ah;   off = i - S1E; }
    else if (i < S3E) { src = W0b;    dst = W0bh;   off = i - S2E; }
    else if (i < S4E) { src = W1a;    dst = W1ah;   off = i - S3E; }
    else if (i < S5E) { src = W1b;    dst = W1bh;   off = i - S4E; }
    else return;
    float4 v = ((const float4*)src)[off];
    ushort4 o;
    o.x = f2bf(v.x); o.y = f2bf(v.y); o.z = f2bf(v.z); o.w = f2bf(v.w);
    ((ushort4*)dst)[off] = o;
}

// ---- 128x64x64 bf16 MFMA GEMM (async gld_lds staging), XCD-swizzled, ----
// ---- head-softmax-fused; blocks [672,688) do target classification. -----
__global__ __launch_bounds__(256, 3) void gemm_sw(
    const unsigned short* __restrict__ Ah,
    const unsigned short* __restrict__ Wheadh, const unsigned short* __restrict__ W0ah,
    const unsigned short* __restrict__ W1ah,
    const int* __restrict__ target,
    float* __restrict__ Shead, float* __restrict__ g0, float* __restrict__ g1,
    float* __restrict__ th,
    unsigned short* __restrict__ XA0h, unsigned short* __restrict__ XA1h,
    int* __restrict__ cnt, int* __restrict__ l0, int* __restrict__ l1)
{
    const int id = blockIdx.x;
    if (id >= 672) {
        int t = (id - 672) * 256 + threadIdx.x;
        if (t < TOK) {
            int tg = target[t];
            if (tg >= NSHORT && tg < NSHORT + C0) {
                int i = atomicAdd(&cnt[0], 1); l0[i] = t;
            } else if (tg >= NSHORT + C0) {
                int i = atomicAdd(&cnt[1], 1); l1[i] = t;
            }
        }
        return;
    }
    const int xcd = id & 7, j = id >> 3;
    const int bx = j % 21, by = xcd + 8 * (j / 21);

    const unsigned short* Bh; int nrows, bn, seg, ldY; unsigned short* Yh;
    if (bx < 16)      { seg = 0; Bh = Wheadh; nrows = NHEAD; bn = bx * 64;        Yh = nullptr; ldY = 0; }
    else if (bx < 20) { seg = 1; Bh = W0ah;   nrows = K0;    bn = (bx - 16) * 64; Yh = XA0h;    ldY = K0; }
    else              { seg = 2; Bh = W1ah;   nrows = K1;    bn = 0;              Yh = XA1h;    ldY = K1; }
    const int bm = by * 128;

    __shared__ short ldsA[2][8192];
    __shared__ short ldsB[2][4096];
    const int tid = threadIdx.x, wv = tid >> 6, lane = tid & 63;
    const int nn = lane & 15, q = lane >> 4;
    const int wr = wv >> 1, wc = wv & 1;

    float4v acc[4][2];
    #pragma unroll
    for (int i = 0; i < 4; ++i)
        #pragma unroll
        for (int jj = 0; jj < 2; ++jj) acc[i][jj] = (float4v){0.f, 0.f, 0.f, 0.f};

    auto stage = [&](int b, int kk) {
        #pragma unroll
        for (int i2 = 0; i2 < 6; ++i2) {
            int ch = wv * 6 + i2;
            if (ch < 16) {
                int rg = ch >> 1, kc = ch & 1;
                int row = bm + rg * 16 + nn;
                gld_lds16(Ah + (size_t)row * DIM + kk + kc * 32 + q * 8, &ldsA[b][ch * 512]);
            } else {
                int bc = ch - 16, rg = bc >> 1, kc = bc & 1;
                int row = bn + rg * 16 + nn;
                if (row > nrows - 1) row = nrows - 1;
                gld_lds16(Bh + (size_t)row * DIM + kk + kc * 32 + q * 8, &ldsB[b][bc * 512]);
            }
        }
    };

    int buf = 0;
    stage(0, 0);
    __syncthreads();
    for (int s = 0; s < DIM / 64; ++s) {
        if (s + 1 < DIM / 64) stage(buf ^ 1, (s + 1) * 64);
        short8 afr[4][2], bfr[2][2];
        #pragma unroll
        for (int i = 0; i < 4; ++i)
            #pragma unroll
            for (int kc = 0; kc < 2; ++kc)
                afr[i][kc] = *(const short8*)&ldsA[buf][((wr * 4 + i) * 2 + kc) * 512 + lane * 8];
        #pragma unroll
        for (int jj = 0; jj < 2; ++jj)
            #pragma unroll
            for (int kc = 0; kc < 2; ++kc)
                bfr[jj][kc] = *(const short8*)&ldsB[buf][((wc * 2 + jj) * 2 + kc) * 512 + lane * 8];
        #pragma unroll
        for (int kc = 0; kc < 2; ++kc)
            #pragma unroll
            for (int i = 0; i < 4; ++i)
                #pragma unroll
                for (int jj = 0; jj < 2; ++jj)
                    acc[i][jj] = __builtin_amdgcn_mfma_f32_16x16x32_bf16(afr[i][kc], bfr[jj][kc], acc[i][jj], 0, 0, 0);
        __syncthreads();
        buf ^= 1;
    }

    if (seg == 0) {
        #pragma unroll
        for (int i = 0; i < 4; ++i) {
            int rowr[4], tg[4];
            float s[4] = {0.f, 0.f, 0.f, 0.f};
            #pragma unroll
            for (int r = 0; r < 4; ++r) {
                rowr[r] = bm + wr * 64 + i * 16 + q * 4 + r;
                tg[r] = target[rowr[r]];
            }
            #pragma unroll
            for (int jj = 0; jj < 2; ++jj) {
                int col = bn + wc * 32 + jj * 16 + nn;
                bool cv = (col < NHEAD);
                #pragma unroll
                for (int r = 0; r < 4; ++r) {
                    float v = acc[i][jj][r];
                    if (cv) {
                        s[r] += __expf(v);
                        if (col == 1000) g0[rowr[r]] = v;
                        if (col == 1001) g1[rowr[r]] = v;
                        if (tg[r] < NSHORT && col == tg[r]) th[rowr[r]] = v;
                    }
                }
            }
            #pragma unroll
            for (int off = 1; off < 16; off <<= 1)
                #pragma unroll
                for (int r = 0; r < 4; ++r) s[r] += __shfl_xor(s[r], off, 64);
            if (nn == 0) {
                #pragma unroll
                for (int r = 0; r < 4; ++r) atomicAdd(&Shead[rowr[r]], s[r]);
            }
        }
    } else {
        #pragma unroll
        for (int i = 0; i < 4; ++i)
            #pragma unroll
            for (int jj = 0; jj < 2; ++jj) {
                int col = bn + wc * 32 + jj * 16 + nn;
                if (col < nrows) {
                    #pragma unroll
                    for (int r = 0; r < 4; ++r) {
                        int row = bm + wr * 64 + i * 16 + q * 4 + r;
                        Yh[(size_t)row * ldY + col] = f2bf(acc[i][jj][r]);
                    }
                }
            }
    }
}

// ------- cluster exp-sum body: persistent LDS-staged MFMA + exp -----------
// xt = token-tile index (MT*64 tokens), sp = class split. A in registers,
// B staged via gld_lds dbuf (G ctiles/buffer) into caller-provided LDS.
template<int K, int G, int MT>
__device__ __forceinline__ void cluster_body(
    const unsigned short* __restrict__ XAh, const unsigned short* __restrict__ Wbh,
    int C, const int* __restrict__ list, int n, int xt, int sp, int tps,
    float* __restrict__ psum, short* lds)
{
    constexpr int NCH = K / 32;
    constexpr int CPB = G * NCH;
    constexpr int TT = MT * 64;
    if (xt * TT >= n) return;
    const int tid = threadIdx.x, wv = tid >> 6, lane = tid & 63;
    const int m = lane & 15, q = lane >> 4;
    const int nT = (C + 15) / 16;
    const int T0 = sp * tps;
    const int T1 = min(T0 + tps, nT);
    if (T0 >= nT) return;

    short8 a[MT][NCH];
    #pragma unroll
    for (int t = 0; t < MT; ++t) {
        int iTok = xt * TT + t * 64 + wv * 16 + m;
        int tok = list[(iTok < n) ? iTok : (n - 1)];
        const unsigned short* ap = XAh + (size_t)tok * K + q * 8;
        #pragma unroll
        for (int kc = 0; kc < NCH; ++kc) a[t][kc] = *(const short8*)(ap + kc * 32);
    }

    float s[MT][4] = {};

    auto stage = [&](int b, int Tb) {
        #pragma unroll
        for (int i = 0; i < CPB / 4; ++i) {
            int ch = wv * (CPB / 4) + i;
            int g = ch / NCH, kc = ch % NCH;
            int row = (Tb + g) * 16 + m;
            if (row > C - 1) row = C - 1;
            gld_lds16(Wbh + (size_t)row * K + kc * 32 + q * 8,
                      &lds[(b * CPB + ch) * 512]);
        }
    };

    int buf = 0;
    stage(0, T0);
    __syncthreads();
    for (int Tb = T0; Tb < T1; Tb += G) {
        if (Tb + G < T1) stage(buf ^ 1, Tb + G);
        #pragma unroll
        for (int g = 0; g < G; ++g) {
            if (Tb + g < T1) {
                float4v av[MT];
                #pragma unroll
                for (int t = 0; t < MT; ++t) av[t] = (float4v){0.f, 0.f, 0.f, 0.f};
                #pragma unroll
                for (int kc = 0; kc < NCH; ++kc) {
                    short8 bfr = *(const short8*)&lds[(buf * CPB + g * NCH + kc) * 512 + lane * 8];
                    #pragma unroll
                    for (int t = 0; t < MT; ++t)
                        av[t] = __builtin_amdgcn_mfma_f32_16x16x32_bf16(a[t][kc], bfr, av[t], 0, 0, 0);
                }
                int jcl = (Tb + g) * 16 + m;
                if (jcl < C) {
                    #pragma unroll
                    for (int t = 0; t < MT; ++t)
                        #pragma unroll
                        for (int r = 0; r < 4; ++r) s[t][r] += __expf(av[t][r]);
                }
            }
        }
        __syncthreads();
        buf ^= 1;
    }
    #pragma unroll
    for (int off = 1; off < 16; off <<= 1)
        #pragma unroll
        for (int t = 0; t < MT; ++t)
            #pragma unroll
            for (int r = 0; r < 4; ++r)
                s[t][r] += __shfl_xor(s[t][r], off, 64);
    if (m == 0) {
        #pragma unroll
        for (int t = 0; t < MT; ++t)
            #pragma unroll
            for (int r = 0; r < 4; ++r) {
                int r0 = xt * TT + t * 64 + wv * 16 + q * 4 + r;
                if (r0 < n) psum[(size_t)r0 * PS + sp] = s[t][r];
            }
    }
}

// ------- merged cluster launch: flat grid, c1 ids first (long pole) -------
// id in [0, 1024): c1, sp = id&63 (-> XCD id%8 = sp%8: one split per XCD,
//   B-stripe L2-deduped), xt = id>>6 (16 tiles of 256 tokens, MT=4).
// id in [1024, 3072): c0, likewise (32 tiles of 128 tokens, MT=2).
#define NB1 (16 * 64)
#define NB0 (32 * 64)
__global__ __launch_bounds__(256) void cluster_merged(
    const unsigned short* __restrict__ XA0h, const unsigned short* __restrict__ W0bh,
    const unsigned short* __restrict__ XA1h, const unsigned short* __restrict__ W1bh,
    const int* __restrict__ l0, const int* __restrict__ l1,
    const int* __restrict__ cnt, int tps0, int tps1,
    float* __restrict__ psum0, float* __restrict__ psum1)
{
    __shared__ short lds[2 * 16 * 512];   // 32 KB, shared by both bodies
    int id = blockIdx.x;
    if (id < NB1) {
        cluster_body<K1, 4, 4>(XA1h, W1bh, C1, l1, cnt[1],
                               id >> 6, id & 63, tps1, psum1, lds);
    } else {
        id -= NB1;
        cluster_body<K0, 2, 2>(XA0h, W0bh, C0, l0, cnt[0],
                               id >> 6, id & 63, tps0, psum0, lds);
    }
}

// ------- finish: shortlist out + cluster target dot/psum/gate + loss ------
__global__ __launch_bounds__(256) void finish_kernel(
    const unsigned short* __restrict__ XA0h, const unsigned short* __restrict__ W0bh,
    const unsigned short* __restrict__ XA1h, const unsigned short* __restrict__ W1bh,
    const int* __restrict__ l0, const int* __restrict__ l1,
    const int* __restrict__ cnt, const int* __restrict__ target,
    const float* __restrict__ psum0, const float* __restrict__ psum1,
    const float* __restrict__ Shead, const float* __restrict__ g0,
    const float* __restrict__ g1, const float* __restrict__ th,
    int tps0, int tps1, float* __restrict__ out, float* __restrict__ loss)
{
    const int y = blockIdx.y;
    const int tid = threadIdx.x, wv = tid >> 6, lane = tid & 63;
    float contrib = 0.f;
    if (y == 2) {
        int t = blockIdx.x * 256 + tid;
        if (t < TOK) {
            int tg = target[t];
            if (tg < NSHORT) {
                float v = th[t] - logf(Shead[t]);
                out[t] = v;
                contrib = v;
            }
        }
    } else {
        const int ci = y;
        const int n = cnt[ci];
        int i = blockIdx.x * 4 + wv;
        if (i < n) {
            const int* list = ci ? l1 : l0;
            int tok = list[i];
            float dot = 0.f, S = 0.f;
            if (ci == 0) {
                int tg = target[tok] - NSHORT;
                const unsigned short* xp = XA0h + (size_t)tok * K0;
                const unsigned short* wp = W0bh + (size_t)tg * K0;
                #pragma unroll
                for (int k = 0; k < K0 / 64; ++k)
                    dot += bf2f(xp[lane + k * 64]) * bf2f(wp[lane + k * 64]);
                int nT = (C0 + 15) / 16;
                if (lane * tps0 < nT) S = psum0[(size_t)i * PS + lane];
            } else {
                int tg = target[tok] - (NSHORT + C0);
                dot = bf2f(XA1h[(size_t)tok * K1 + lane]) * bf2f(W1bh[(size_t)tg * K1 + lane]);
                int nT = (C1 + 15) / 16;
                if (lane * tps1 < nT) S = psum1[(size_t)i * PS + lane];
            }
            #pragma unroll
            for (int off = 32; off; off >>= 1) {
                dot += __shfl_xor(dot, off, 64);
                S   += __shfl_xor(S, off, 64);
            }
            if (lane == 0) {
                float gate = (ci ? g1[tok] : g0[tok]) - logf(Shead[tok]);
                float v = dot - logf(S) + gate;
                out[tok] = v;
                contrib = v;
            }
        }
    }
    __shared__ float red[4];
    #pragma unroll
    for (int off = 32; off; off >>= 1) contrib += __shfl_xor(contrib, off, 64);
    if (lane == 0) red[wv] = contrib;
    __syncthreads();
    if (tid == 0) {
        float t = red[0] + red[1] + red[2] + red[3];
        if (t != 0.f) atomicAdd(loss, -t / (float)TOK);
    }
}

extern "C" void kernel_launch(void* const* d_in, const int* in_sizes, int n_in,
                              void* d_out, int out_size, void* d_ws, size_t ws_size,
                              hipStream_t stream) {
    const float* x      = (const float*)d_in[0];
    const int*   target = (const int*)  d_in[1];
    const float* W_head = (const float*)d_in[2];
    const float* W0a    = (const float*)d_in[3];
    const float* W0b    = (const float*)d_in[4];
    const float* W1a    = (const float*)d_in[5];
    const float* W1b    = (const float*)d_in[6];
    float* out  = (float*)d_out;
    float* loss = out + TOK;

    float* ws     = (float*)d_ws;
    float* Shead  = ws;                               // 4096
    float* g0     = Shead + TOK;                      // 4096
    float* g1     = g0 + TOK;                         // 4096
    float* th     = g1 + TOK;                         // 4096
    float* psum0  = th + TOK;                         // 4096*64
    float* psum1  = psum0 + (size_t)TOK * PS;         // 4096*64
    unsigned short* xh     = (unsigned short*)(psum1 + (size_t)TOK * PS);
    unsigned short* Wheadh = xh + (size_t)TOK * DIM;
    unsigned short* W0ah   = Wheadh + (size_t)NHEAD * DIM;
    unsigned short* W0bh   = W0ah + (size_t)K0 * DIM;
    unsigned short* W1ah   = W0bh + (size_t)C0 * K0;
    unsigned short* W1bh   = W1ah + (size_t)K1 * DIM;
    unsigned short* XA0h   = W1bh + (size_t)C1 * K1;
    unsigned short* XA1h   = XA0h + (size_t)TOK * K0;
    int* cnt = (int*)(XA1h + (size_t)TOK * K1);
    int* l0  = cnt + 8;
    int* l1  = l0 + TOK;

    int tps0 = ((C0 + 15) / 16 + SP0 - 1) / SP0;   // 9
    int tps1 = ((C1 + 15) / 16 + SP1 - 1) / SP1;   // 40

    megacast_kernel<<<(S5E + 255) / 256, 256, 0, stream>>>(
        x, W_head, W0a, W0b, W1a, W1b, xh, Wheadh, W0ah, W0bh, W1ah, W1bh,
        cnt, Shead, loss);

    gemm_sw<<<688, 256, 0, stream>>>(
        xh, Wheadh, W0ah, W1ah, target, Shead, g0, g1, th, XA0h, XA1h,
        cnt, l0, l1);

    cluster_merged<<<NB1 + NB0, 256, 0, stream>>>(
        XA0h, W0bh, XA1h, W1bh, l0, l1, cnt, tps0, tps1, psum0, psum1);

    finish_kernel<<<dim3(1024, 3), 256, 0, stream>>>(
        XA0h, W0bh, XA1h, W1bh, l0, l1, cnt, target, psum0, psum1,
        Shead, g0, g1, th, tps0, tps1, out, loss);
}

// Round 14
// 183.730 us; speedup vs baseline: 1.6499x; 1.0164x over previous
//
#include <hip/hip_runtime.h>
#include <math.h>

#define TOK    4096
#define DIM    1024
#define NHEAD  1002
#define NSHORT 1000
#define C0     9000
#define K0     256
#define C1     40257
#define K1     64
#define SP0    64
#define SP1    64
#define PS     64

typedef __attribute__((ext_vector_type(8))) short short8;
typedef __attribute__((ext_vector_type(4))) float float4v;

__device__ __forceinline__ void gld_lds16(const void* g, void* l) {
    __builtin_amdgcn_global_load_lds(
        (const __attribute__((address_space(1))) unsigned int*)g,
        (__attribute__((address_space(3))) unsigned int*)l,
        16, 0, 0);
}

__device__ __forceinline__ unsigned short f2bf(float f) {
    unsigned int u = __float_as_uint(f);
    return (unsigned short)((u + 0x7FFFu + ((u >> 16) & 1u)) >> 16);
}

__device__ __forceinline__ float bf2f(unsigned short h) {
    return __uint_as_float(((unsigned int)h) << 16);
}

// -------- fp32->bf16 casts for x + small weights (+ init) -----------------
// W0b/W1b casts moved into gemm_sw's trailing blocks (overlap with GEMM).
#define S0E (TOK * DIM / 4)
#define S1E (S0E + NHEAD * DIM / 4)
#define S2E (S1E + K0 * DIM / 4)
#define S3E (S2E + K1 * DIM / 4)
__global__ __launch_bounds__(256) void megacast_kernel(
    const float* __restrict__ x, const float* __restrict__ W_head,
    const float* __restrict__ W0a, const float* __restrict__ W1a,
    unsigned short* __restrict__ xh, unsigned short* __restrict__ Wheadh,
    unsigned short* __restrict__ W0ah, unsigned short* __restrict__ W1ah,
    int* __restrict__ cnt, float* __restrict__ Shead, float* __restrict__ loss)
{
    int i = blockIdx.x * 256 + threadIdx.x;
    if (i == 0) { cnt[0] = 0; cnt[1] = 0; loss[0] = 0.f; }
    if (i < TOK / 4) ((float4*)Shead)[i] = (float4){0.f, 0.f, 0.f, 0.f};
    const float* src; unsigned short* dst; int off;
    if      (i < S0E) { src = x;      dst = xh;     off = i; }
    else if (i < S1E) { src = W_head; dst = Wheadh; off = i - S0E; }
    else if (i < S2E) { src = W0a;    dst = W0ah;   off = i - S1E; }
    else if (i < S3E) { src = W1a;    dst = W1ah;   off = i - S2E; }
    else return;
    float4 v = ((const float4*)src)[off];
    ushort4 o;
    o.x = f2bf(v.x); o.y = f2bf(v.y); o.z = f2bf(v.z); o.w = f2bf(v.w);
    ((ushort4*)dst)[off] = o;
}

// ---- 128x64x64 bf16 MFMA GEMM (async gld_lds staging), XCD-swizzled, ----
// head-softmax-fused. Grid: [0,672) GEMM, [672,688) classify,
// [688, 688+CASTB) stream-cast W0b/W1b (consumed only by cluster_merged —
// overlaps the GEMM's latency stalls with pure HBM streaming).
#define C0E (C0 * K0 / 4)
#define C1E (C0E + C1 * K1 / 4)
#define CASTB ((C1E + 255) / 256)
__global__ __launch_bounds__(256, 3) void gemm_sw(
    const unsigned short* __restrict__ Ah,
    const unsigned short* __restrict__ Wheadh, const unsigned short* __restrict__ W0ah,
    const unsigned short* __restrict__ W1ah,
    const float* __restrict__ W0b, const float* __restrict__ W1b,
    unsigned short* __restrict__ W0bh, unsigned short* __restrict__ W1bh,
    const int* __restrict__ target,
    float* __restrict__ Shead, float* __restrict__ g0, float* __restrict__ g1,
    float* __restrict__ th,
    unsigned short* __restrict__ XA0h, unsigned short* __restrict__ XA1h,
    int* __restrict__ cnt, int* __restrict__ l0, int* __restrict__ l1)
{
    const int id = blockIdx.x;
    if (id >= 688) {
        // streaming cast blocks: W0b then W1b
        int i = (id - 688) * 256 + threadIdx.x;
        const float* src; unsigned short* dst; int off;
        if      (i < C0E) { src = W0b; dst = W0bh; off = i; }
        else if (i < C1E) { src = W1b; dst = W1bh; off = i - C0E; }
        else return;
        float4 v = ((const float4*)src)[off];
        ushort4 o;
        o.x = f2bf(v.x); o.y = f2bf(v.y); o.z = f2bf(v.z); o.w = f2bf(v.w);
        ((ushort4*)dst)[off] = o;
        return;
    }
    if (id >= 672) {
        int t = (id - 672) * 256 + threadIdx.x;
        if (t < TOK) {
            int tg = target[t];
            if (tg >= NSHORT && tg < NSHORT + C0) {
                int i = atomicAdd(&cnt[0], 1); l0[i] = t;
            } else if (tg >= NSHORT + C0) {
                int i = atomicAdd(&cnt[1], 1); l1[i] = t;
            }
        }
        return;
    }
    const int xcd = id & 7, j = id >> 3;
    const int bx = j % 21, by = xcd + 8 * (j / 21);

    const unsigned short* Bh; int nrows, bn, seg, ldY; unsigned short* Yh;
    if (bx < 16)      { seg = 0; Bh = Wheadh; nrows = NHEAD; bn = bx * 64;        Yh = nullptr; ldY = 0; }
    else if (bx < 20) { seg = 1; Bh = W0ah;   nrows = K0;    bn = (bx - 16) * 64; Yh = XA0h;    ldY = K0; }
    else              { seg = 2; Bh = W1ah;   nrows = K1;    bn = 0;              Yh = XA1h;    ldY = K1; }
    const int bm = by * 128;

    __shared__ short ldsA[2][8192];
    __shared__ short ldsB[2][4096];
    const int tid = threadIdx.x, wv = tid >> 6, lane = tid & 63;
    const int nn = lane & 15, q = lane >> 4;
    const int wr = wv >> 1, wc = wv & 1;

    float4v acc[4][2];
    #pragma unroll
    for (int i = 0; i < 4; ++i)
        #pragma unroll
        for (int jj = 0; jj < 2; ++jj) acc[i][jj] = (float4v){0.f, 0.f, 0.f, 0.f};

    auto stage = [&](int b, int kk) {
        #pragma unroll
        for (int i2 = 0; i2 < 6; ++i2) {
            int ch = wv * 6 + i2;
            if (ch < 16) {
                int rg = ch >> 1, kc = ch & 1;
                int row = bm + rg * 16 + nn;
                gld_lds16(Ah + (size_t)row * DIM + kk + kc * 32 + q * 8, &ldsA[b][ch * 512]);
            } else {
                int bc = ch - 16, rg = bc >> 1, kc = bc & 1;
                int row = bn + rg * 16 + nn;
                if (row > nrows - 1) row = nrows - 1;
                gld_lds16(Bh + (size_t)row * DIM + kk + kc * 32 + q * 8, &ldsB[b][bc * 512]);
            }
        }
    };

    int buf = 0;
    stage(0, 0);
    __syncthreads();
    for (int s = 0; s < DIM / 64; ++s) {
        if (s + 1 < DIM / 64) stage(buf ^ 1, (s + 1) * 64);
        short8 afr[4][2], bfr[2][2];
        #pragma unroll
        for (int i = 0; i < 4; ++i)
            #pragma unroll
            for (int kc = 0; kc < 2; ++kc)
                afr[i][kc] = *(const short8*)&ldsA[buf][((wr * 4 + i) * 2 + kc) * 512 + lane * 8];
        #pragma unroll
        for (int jj = 0; jj < 2; ++jj)
            #pragma unroll
            for (int kc = 0; kc < 2; ++kc)
                bfr[jj][kc] = *(const short8*)&ldsB[buf][((wc * 2 + jj) * 2 + kc) * 512 + lane * 8];
        #pragma unroll
        for (int kc = 0; kc < 2; ++kc)
            #pragma unroll
            for (int i = 0; i < 4; ++i)
                #pragma unroll
                for (int jj = 0; jj < 2; ++jj)
                    acc[i][jj] = __builtin_amdgcn_mfma_f32_16x16x32_bf16(afr[i][kc], bfr[jj][kc], acc[i][jj], 0, 0, 0);
        __syncthreads();
        buf ^= 1;
    }

    if (seg == 0) {
        #pragma unroll
        for (int i = 0; i < 4; ++i) {
            int rowr[4], tg[4];
            float s[4] = {0.f, 0.f, 0.f, 0.f};
            #pragma unroll
            for (int r = 0; r < 4; ++r) {
                rowr[r] = bm + wr * 64 + i * 16 + q * 4 + r;
                tg[r] = target[rowr[r]];
            }
            #pragma unroll
            for (int jj = 0; jj < 2; ++jj) {
                int col = bn + wc * 32 + jj * 16 + nn;
                bool cv = (col < NHEAD);
                #pragma unroll
                for (int r = 0; r < 4; ++r) {
                    float v = acc[i][jj][r];
                    if (cv) {
                        s[r] += __expf(v);
                        if (col == 1000) g0[rowr[r]] = v;
                        if (col == 1001) g1[rowr[r]] = v;
                        if (tg[r] < NSHORT && col == tg[r]) th[rowr[r]] = v;
                    }
                }
            }
            #pragma unroll
            for (int off = 1; off < 16; off <<= 1)
                #pragma unroll
                for (int r = 0; r < 4; ++r) s[r] += __shfl_xor(s[r], off, 64);
            if (nn == 0) {
                #pragma unroll
                for (int r = 0; r < 4; ++r) atomicAdd(&Shead[rowr[r]], s[r]);
            }
        }
    } else {
        #pragma unroll
        for (int i = 0; i < 4; ++i)
            #pragma unroll
            for (int jj = 0; jj < 2; ++jj) {
                int col = bn + wc * 32 + jj * 16 + nn;
                if (col < nrows) {
                    #pragma unroll
                    for (int r = 0; r < 4; ++r) {
                        int row = bm + wr * 64 + i * 16 + q * 4 + r;
                        Yh[(size_t)row * ldY + col] = f2bf(acc[i][jj][r]);
                    }
                }
            }
    }
}

// ------- cluster exp-sum body: persistent LDS-staged MFMA + exp -----------
template<int K, int G, int MT>
__device__ __forceinline__ void cluster_body(
    const unsigned short* __restrict__ XAh, const unsigned short* __restrict__ Wbh,
    int C, const int* __restrict__ list, int n, int xt, int sp, int tps,
    float* __restrict__ psum, short* lds)
{
    constexpr int NCH = K / 32;
    constexpr int CPB = G * NCH;
    constexpr int TT = MT * 64;
    if (xt * TT >= n) return;
    const int tid = threadIdx.x, wv = tid >> 6, lane = tid & 63;
    const int m = lane & 15, q = lane >> 4;
    const int nT = (C + 15) / 16;
    const int T0 = sp * tps;
    const int T1 = min(T0 + tps, nT);
    if (T0 >= nT) return;

    short8 a[MT][NCH];
    #pragma unroll
    for (int t = 0; t < MT; ++t) {
        int iTok = xt * TT + t * 64 + wv * 16 + m;
        int tok = list[(iTok < n) ? iTok : (n - 1)];
        const unsigned short* ap = XAh + (size_t)tok * K + q * 8;
        #pragma unroll
        for (int kc = 0; kc < NCH; ++kc) a[t][kc] = *(const short8*)(ap + kc * 32);
    }

    float s[MT][4] = {};

    auto stage = [&](int b, int Tb) {
        #pragma unroll
        for (int i = 0; i < CPB / 4; ++i) {
            int ch = wv * (CPB / 4) + i;
            int g = ch / NCH, kc = ch % NCH;
            int row = (Tb + g) * 16 + m;
            if (row > C - 1) row = C - 1;
            gld_lds16(Wbh + (size_t)row * K + kc * 32 + q * 8,
                      &lds[(b * CPB + ch) * 512]);
        }
    };

    int buf = 0;
    stage(0, T0);
    __syncthreads();
    for (int Tb = T0; Tb < T1; Tb += G) {
        if (Tb + G < T1) stage(buf ^ 1, Tb + G);
        #pragma unroll
        for (int g = 0; g < G; ++g) {
            if (Tb + g < T1) {
                float4v av[MT];
                #pragma unroll
                for (int t = 0; t < MT; ++t) av[t] = (float4v){0.f, 0.f, 0.f, 0.f};
                #pragma unroll
                for (int kc = 0; kc < NCH; ++kc) {
                    short8 bfr = *(const short8*)&lds[(buf * CPB + g * NCH + kc) * 512 + lane * 8];
                    #pragma unroll
                    for (int t = 0; t < MT; ++t)
                        av[t] = __builtin_amdgcn_mfma_f32_16x16x32_bf16(a[t][kc], bfr, av[t], 0, 0, 0);
                }
                int jcl = (Tb + g) * 16 + m;
                if (jcl < C) {
                    #pragma unroll
                    for (int t = 0; t < MT; ++t)
                        #pragma unroll
                        for (int r = 0; r < 4; ++r) s[t][r] += __expf(av[t][r]);
                }
            }
        }
        __syncthreads();
        buf ^= 1;
    }
    #pragma unroll
    for (int off = 1; off < 16; off <<= 1)
        #pragma unroll
        for (int t = 0; t < MT; ++t)
            #pragma unroll
            for (int r = 0; r < 4; ++r)
                s[t][r] += __shfl_xor(s[t][r], off, 64);
    if (m == 0) {
        #pragma unroll
        for (int t = 0; t < MT; ++t)
            #pragma unroll
            for (int r = 0; r < 4; ++r) {
                int r0 = xt * TT + t * 64 + wv * 16 + q * 4 + r;
                if (r0 < n) psum[(size_t)r0 * PS + sp] = s[t][r];
            }
    }
}

// ------- merged cluster launch: flat grid, c1 ids first (long pole) -------
#define NB1 (16 * 64)
#define NB0 (32 * 64)
__global__ __launch_bounds__(256) void cluster_merged(
    const unsigned short* __restrict__ XA0h, const unsigned short* __restrict__ W0bh,
    const unsigned short* __restrict__ XA1h, const unsigned short* __restrict__ W1bh,
    const int* __restrict__ l0, const int* __restrict__ l1,
    const int* __restrict__ cnt, int tps0, int tps1,
    float* __restrict__ psum0, float* __restrict__ psum1)
{
    __shared__ short lds[2 * 16 * 512];   // 32 KB, shared by both bodies
    int id = blockIdx.x;
    if (id < NB1) {
        cluster_body<K1, 4, 4>(XA1h, W1bh, C1, l1, cnt[1],
                               id >> 6, id & 63, tps1, psum1, lds);
    } else {
        id -= NB1;
        cluster_body<K0, 2, 2>(XA0h, W0bh, C0, l0, cnt[0],
                               id >> 6, id & 63, tps0, psum0, lds);
    }
}

// ------- finish: shortlist out + cluster target dot/psum/gate + loss ------
__global__ __launch_bounds__(256) void finish_kernel(
    const unsigned short* __restrict__ XA0h, const unsigned short* __restrict__ W0bh,
    const unsigned short* __restrict__ XA1h, const unsigned short* __restrict__ W1bh,
    const int* __restrict__ l0, const int* __restrict__ l1,
    const int* __restrict__ cnt, const int* __restrict__ target,
    const float* __restrict__ psum0, const float* __restrict__ psum1,
    const float* __restrict__ Shead, const float* __restrict__ g0,
    const float* __restrict__ g1, const float* __restrict__ th,
    int tps0, int tps1, float* __restrict__ out, float* __restrict__ loss)
{
    const int y = blockIdx.y;
    const int tid = threadIdx.x, wv = tid >> 6, lane = tid & 63;
    float contrib = 0.f;
    if (y == 2) {
        int t = blockIdx.x * 256 + tid;
        if (t < TOK) {
            int tg = target[t];
            if (tg < NSHORT) {
                float v = th[t] - logf(Shead[t]);
                out[t] = v;
                contrib = v;
            }
        }
    } else {
        const int ci = y;
        const int n = cnt[ci];
        int i = blockIdx.x * 4 + wv;
        if (i < n) {
            const int* list = ci ? l1 : l0;
            int tok = list[i];
            float dot = 0.f, S = 0.f;
            if (ci == 0) {
                int tg = target[tok] - NSHORT;
                const unsigned short* xp = XA0h + (size_t)tok * K0;
                const unsigned short* wp = W0bh + (size_t)tg * K0;
                #pragma unroll
                for (int k = 0; k < K0 / 64; ++k)
                    dot += bf2f(xp[lane + k * 64]) * bf2f(wp[lane + k * 64]);
                int nT = (C0 + 15) / 16;
                if (lane * tps0 < nT) S = psum0[(size_t)i * PS + lane];
            } else {
                int tg = target[tok] - (NSHORT + C0);
                dot = bf2f(XA1h[(size_t)tok * K1 + lane]) * bf2f(W1bh[(size_t)tg * K1 + lane]);
                int nT = (C1 + 15) / 16;
                if (lane * tps1 < nT) S = psum1[(size_t)i * PS + lane];
            }
            #pragma unroll
            for (int off = 32; off; off >>= 1) {
                dot += __shfl_xor(dot, off, 64);
                S   += __shfl_xor(S, off, 64);
            }
            if (lane == 0) {
                float gate = (ci ? g1[tok] : g0[tok]) - logf(Shead[tok]);
                float v = dot - logf(S) + gate;
                out[tok] = v;
                contrib = v;
            }
        }
    }
    __shared__ float red[4];
    #pragma unroll
    for (int off = 32; off; off >>= 1) contrib += __shfl_xor(contrib, off, 64);
    if (lane == 0) red[wv] = contrib;
    __syncthreads();
    if (tid == 0) {
        float t = red[0] + red[1] + red[2] + red[3];
        if (t != 0.f) atomicAdd(loss, -t / (float)TOK);
    }
}

extern "C" void kernel_launch(void* const* d_in, const int* in_sizes, int n_in,
                              void* d_out, int out_size, void* d_ws, size_t ws_size,
                              hipStream_t stream) {
    const float* x      = (const float*)d_in[0];
    const int*   target = (const int*)  d_in[1];
    const float* W_head = (const float*)d_in[2];
    const float* W0a    = (const float*)d_in[3];
    const float* W0b    = (const float*)d_in[4];
    const float* W1a    = (const float*)d_in[5];
    const float* W1b    = (const float*)d_in[6];
    float* out  = (float*)d_out;
    float* loss = out + TOK;

    float* ws     = (float*)d_ws;
    float* Shead  = ws;                               // 4096
    float* g0     = Shead + TOK;                      // 4096
    float* g1     = g0 + TOK;                         // 4096
    float* th     = g1 + TOK;                         // 4096
    float* psum0  = th + TOK;                         // 4096*64
    float* psum1  = psum0 + (size_t)TOK * PS;         // 4096*64
    unsigned short* xh     = (unsigned short*)(psum1 + (size_t)TOK * PS);
    unsigned short* Wheadh = xh + (size_t)TOK * DIM;
    unsigned short* W0ah   = Wheadh + (size_t)NHEAD * DIM;
    unsigned short* W0bh   = W0ah + (size_t)K0 * DIM;
    unsigned short* W1ah   = W0bh + (size_t)C0 * K0;
    unsigned short* W1bh   = W1ah + (size_t)K1 * DIM;
    unsigned short* XA0h   = W1bh + (size_t)C1 * K1;
    unsigned short* XA1h   = XA0h + (size_t)TOK * K0;
    int* cnt = (int*)(XA1h + (size_t)TOK * K1);
    int* l0  = cnt + 8;
    int* l1  = l0 + TOK;

    int tps0 = ((C0 + 15) / 16 + SP0 - 1) / SP0;   // 9
    int tps1 = ((C1 + 15) / 16 + SP1 - 1) / SP1;   // 40

    megacast_kernel<<<(S3E + 255) / 256, 256, 0, stream>>>(
        x, W_head, W0a, W1a, xh, Wheadh, W0ah, W1ah, cnt, Shead, loss);

    gemm_sw<<<688 + CASTB, 256, 0, stream>>>(
        xh, Wheadh, W0ah, W1ah, W0b, W1b, W0bh, W1bh,
        target, Shead, g0, g1, th, XA0h, XA1h, cnt, l0, l1);

    cluster_merged<<<NB1 + NB0, 256, 0, stream>>>(
        XA0h, W0bh, XA1h, W1bh, l0, l1, cnt, tps0, tps1, psum0, psum1);

    finish_kernel<<<dim3(1024, 3), 256, 0, stream>>>(
        XA0h, W0bh, XA1h, W1bh, l0, l1, cnt, target, psum0, psum1,
        Shead, g0, g1, th, tps0, tps1, out, loss);
}